// Round 8
// baseline (362.680 us; speedup 1.0000x reference)
//
#include <hip/hip_runtime.h>

typedef _Float16 f16;
typedef unsigned int uint;
typedef f16 f16x2 __attribute__((ext_vector_type(2)));
typedef f16 f16x8 __attribute__((ext_vector_type(8)));
typedef __fp16 h16x2 __attribute__((ext_vector_type(2)));
typedef float f32x4 __attribute__((ext_vector_type(4)));

#define Bn 512
#define Ln 128
#define Dn 128
#define Cn 512   // 4 gates * D
#define TS 136   // padded t-extent (8 pad rows -> unguarded prefetch)

__device__ __forceinline__ float fdot2f(uint a, uint b, float c) {
#if __has_builtin(__builtin_amdgcn_fdot2)
  return __builtin_amdgcn_fdot2(__builtin_bit_cast(f16x2, a),
                                __builtin_bit_cast(f16x2, b), c, false);
#else
  f16x2 av = __builtin_bit_cast(f16x2, a), bv = __builtin_bit_cast(f16x2, b);
  return c + (float)av[0] * (float)bv[0] + (float)av[1] * (float)bv[1];
#endif
}

__device__ __forceinline__ uint pk2(float a, float b) {
#if __has_builtin(__builtin_amdgcn_cvt_pkrtz)
  h16x2 v = __builtin_amdgcn_cvt_pkrtz(a, b);
  return __builtin_bit_cast(uint, v);
#else
  f16x2 v; v[0] = (f16)a; v[1] = (f16)b;
  return __builtin_bit_cast(uint, v);
#endif
}

// ---------------- convert: W -> MFMA-fragment-ordered f16 (WhF), R -> transposed f16 ----------------
__global__ __launch_bounds__(256) void k_convert(const float* __restrict__ Wg,
                                                 const float* __restrict__ Rg,
                                                 f16* __restrict__ WhF,
                                                 f16* __restrict__ RT) {
  int i = blockIdx.x * 256 + threadIdx.x;
  const int nWfrag = 2 * 4 * 32 * 64;   // 16384 groups of 8 f16
  if (i < nWfrag) {
    int lane = i & 63;
    int ii   = (i >> 6) & 31;
    int kk   = (i >> 11) & 3;
    int l    = i >> 13;
    int c = ii * 16 + (lane & 15);
    int d = kk * 32 + ((lane >> 4) << 3);
    const float* src = Wg + ((size_t)(l * 512 + c) * 128 + d);
    f16* dst = WhF + (size_t)i * 8;
    #pragma unroll
    for (int j = 0; j < 8; ++j) dst[j] = (f16)src[j];
  } else {
    int j = i - nWfrag;  // 32768 = 2*4*4*32*32
    if (j < 32768) {
      int dd = j & 31;
      int e  = (j >> 5) & 31;
      int hh = (j >> 10) & 3;
      int g  = (j >> 12) & 3;
      int l  = j >> 14;
      RT[j] = (f16)Rg[((((l * 4 + g) * 4 + hh) * 32 + dd) * 32) + e];
    }
  }
}

// ---------------- fused per-sequence pipeline ----------------
// 512 blocks x 128 threads; block = 1 sequence. Phases:
//   E: embed + LN0 -> xnL (LDS) + x residual (global)
//   G: MFMA GEMM (A from LDS, B from WhF fragments) -> preP (global, L2-warm)
//   S: r6-style scan (wave-local h exchange, deferred in-lane groupnorm)
//   LN1, G1, S1 (pooled accumulate)
__global__ __launch_bounds__(128, 1) void k_fused(const int* __restrict__ ids,
                                                  const float* __restrict__ emb,
                                                  const float* __restrict__ lnw,
                                                  const float* __restrict__ lnb,
                                                  const f16* __restrict__ WhF,
                                                  const f16* __restrict__ RT,
                                                  const float* __restrict__ bg,
                                                  const float* __restrict__ gnw,
                                                  float* __restrict__ x,
                                                  uint2* __restrict__ preP,
                                                  float* __restrict__ pooled) {
  __shared__ __align__(16) f16 xnL[128 * TS];   // 34,816 B
  __shared__ __align__(16) f16 hsh[2][64];
  const int tid = threadIdx.x;
  const int b = blockIdx.x;
  float* xb  = x   + (size_t)b * TS * Dn;       // [136][128] f32
  uint2* ppb = preP + (size_t)b * TS * Dn;      // [136][128] uint2

  // ---- LN into LDS (optionally fused with embed gather) ----
  auto ln_phase = [&](const float* lwp, const float* lbp, bool do_embed) {
    int r4 = tid >> 2, cq = tid & 3;
    const float4* lwv = (const float4*)(lwp + cq * 32);
    const float4* lbv = (const float4*)(lbp + cq * 32);
    #pragma unroll 1
    for (int pass = 0; pass < 4; ++pass) {
      int t = pass * 32 + r4;
      const float4* src;
      if (do_embed) {
        int id = ids[b * Ln + t];
        src = (const float4*)(emb + (size_t)id * Dn + cq * 32);
      } else {
        src = (const float4*)(xb + (size_t)t * Dn + cq * 32);
      }
      float4 v[8]; float s1 = 0.f, s2 = 0.f;
      #pragma unroll
      for (int j = 0; j < 8; ++j) {
        v[j] = src[j];
        s1 += v[j].x + v[j].y + v[j].z + v[j].w;
        s2 += v[j].x*v[j].x + v[j].y*v[j].y + v[j].z*v[j].z + v[j].w*v[j].w;
      }
      s1 += __shfl_xor(s1, 1); s2 += __shfl_xor(s2, 1);
      s1 += __shfl_xor(s1, 2); s2 += __shfl_xor(s2, 2);
      float mu = s1 * (1.f / 128.f);
      float rs = rsqrtf(s2 * (1.f / 128.f) - mu * mu + 1e-5f);
      if (do_embed) {
        float4* xw = (float4*)(xb + (size_t)t * Dn + cq * 32);
        #pragma unroll
        for (int j = 0; j < 8; ++j) xw[j] = v[j];
      }
      uint u[16];
      #pragma unroll
      for (int j = 0; j < 8; ++j) {
        float4 wv = lwv[j], bb = lbv[j];
        u[2*j]   = pk2((v[j].x - mu) * rs * wv.x + bb.x,
                       (v[j].y - mu) * rs * wv.y + bb.y);
        u[2*j+1] = pk2((v[j].z - mu) * rs * wv.z + bb.z,
                       (v[j].w - mu) * rs * wv.w + bb.w);
      }
      uint4* dst = (uint4*)&xnL[t * TS + cq * 32];
      #pragma unroll
      for (int q = 0; q < 4; ++q)
        dst[q] = make_uint4(u[4*q], u[4*q+1], u[4*q+2], u[4*q+3]);
    }
  };

  // ---- GEMM phase: 8 m-tiles, wave w does rows [w*64, w*64+64) ----
  auto gemm_phase = [&](const f16* WhFl, const float* bias) {
    const int w = tid >> 6;
    const int lane = tid & 63;
    const int l16 = lane & 15, quad = lane >> 4;
    float bv[32];
    #pragma unroll
    for (int i = 0; i < 32; ++i) bv[i] = bias[i * 16 + l16];
    const f16* bbase = WhFl + (size_t)lane * 8;
    #pragma unroll 1
    for (int mt = 0; mt < 4; ++mt) {
      int r0 = (w * 4 + mt) * 16;
      f16x8 a[4];
      #pragma unroll
      for (int kk = 0; kk < 4; ++kk)
        a[kk] = *(const f16x8*)&xnL[(r0 + l16) * TS + quad * 8 + kk * 32];
      f32x4 acc[32] = {};
      #pragma unroll
      for (int kk = 0; kk < 4; ++kk) {
        #pragma unroll
        for (int i = 0; i < 32; ++i) {
          f16x8 bf = *(const f16x8*)(bbase + (size_t)(kk * 32 + i) * 512);
          acc[i] = __builtin_amdgcn_mfma_f32_16x16x32_f16(a[kk], bf, acc[i], 0, 0, 0);
        }
      }
      #pragma unroll
      for (int r = 0; r < 4; ++r) {
        int m = r0 + quad * 4 + r;
        #pragma unroll
        for (int i7 = 0; i7 < 8; ++i7) {
          uint2 vv;
          vv.x = pk2(acc[i7][r]      + bv[i7],      acc[i7 + 8][r]  + bv[i7 + 8]);
          vv.y = pk2(acc[i7 + 16][r] + bv[i7 + 16], acc[i7 + 24][r] + bv[i7 + 24]);
          ppb[(size_t)m * Dn + i7 * 16 + l16] = vv;
        }
      }
    }
  };

  // ---- scan phase (r6 body: no cross-lane ops in the loop) ----
  auto scan_phase = [&](const f16* RTl, const float* gnwp, int last) {
    const int w = tid >> 6;
    const int lane = tid & 63;
    const int d = tid;               // element 0..127
    const int head = d >> 5;
    const int eo = d & 31;
    const int half = lane >> 5;
    const uint one2 = 0x3C003C00u;   // f16 {1,1}

    uint rr[4][16];
    const uint* RT32 = (const uint*)RTl;
    #pragma unroll
    for (int g = 0; g < 4; ++g) {
      const uint* p = RT32 + ((g * 4 + head) * 32 + eo) * 16;
      #pragma unroll
      for (int j = 0; j < 16; ++j) rr[g][j] = p[j];
    }
    const float gw = gnwp[d];
    hsh[w][lane] = (f16)0.f;         // wave-local, DS in-order

    const uint2* pp = ppb + d;
    const float* xp = xb + d;
    float* xo = xb + d;

    uint2 pbuf[8]; float xbuf[8];
    #pragma unroll
    for (int k = 0; k < 8; ++k) { pbuf[k] = pp[(size_t)k * Dn]; xbuf[k] = xp[(size_t)k * Dn]; }

    float cc = 0.f, nc = 0.f, mc = 0.f, psum = 0.f;
    float hprev = 0.f, xprev = 0.f;

    #pragma unroll 1
    for (int t = 0; t < Ln; t += 8) {
      #pragma unroll
      for (int k = 0; k < 8; ++k) {
        int tt = t + k;
        uint2 pc = pbuf[k]; float xc = xbuf[k];
        pbuf[k] = pp[(size_t)(tt + 8) * Dn];   // unguarded: pad rows 128..135
        xbuf[k] = xp[(size_t)(tt + 8) * Dn];

        uint hu[16];
        {
          const uint* hp = (const uint*)&hsh[w][0];
          uint4 q0 = *(const uint4*)(hp + half * 16);
          uint4 q1 = *(const uint4*)(hp + half * 16 + 4);
          uint4 q2 = *(const uint4*)(hp + half * 16 + 8);
          uint4 q3 = *(const uint4*)(hp + half * 16 + 12);
          hu[0]=q0.x; hu[1]=q0.y; hu[2]=q0.z; hu[3]=q0.w;
          hu[4]=q1.x; hu[5]=q1.y; hu[6]=q1.z; hu[7]=q1.w;
          hu[8]=q2.x; hu[9]=q2.y; hu[10]=q2.z; hu[11]=q2.w;
          hu[12]=q3.x; hu[13]=q3.y; hu[14]=q3.z; hu[15]=q3.w;
        }

        // gate dots first (critical path)
        float a0 = 0.f, a1 = 0.f, a2 = 0.f, a3 = 0.f;
        #pragma unroll
        for (int j = 0; j < 16; ++j) {
          a0 = fdot2f(hu[j], rr[0][j], a0);
          a1 = fdot2f(hu[j], rr[1][j], a1);
          a2 = fdot2f(hu[j], rr[2][j], a2);
          a3 = fdot2f(hu[j], rr[3][j], a3);
        }
        // stats for deferred groupnorm of step tt-1 (off-path)
        float s1 = 0.f, s2 = 0.f;
        #pragma unroll
        for (int j = 0; j < 16; ++j) {
          s1 = fdot2f(hu[j], one2, s1);
          s2 = fdot2f(hu[j], hu[j], s2);
        }
        {
          float mu = s1 * (1.f / 32.f);
          float va = s2 * (1.f / 32.f) - mu * mu;
          float ov = xprev + (hprev - mu) * rsqrtf(va + 1e-5f) * gw;
          if (tt > 0) {
            if (last) psum += ov;
            else      xo[(size_t)(tt - 1) * Dn] = ov;
          }
        }

        f16x2 lo = __builtin_bit_cast(f16x2, pc.x);
        f16x2 hi = __builtin_bit_cast(f16x2, pc.y);
        float it = (float)lo[0] + a0, ft = (float)lo[1] + a1;
        float zt = (float)hi[0] + a2, ot = (float)hi[1] + a3;

        float mn = fmaxf(ft + mc, it);
        float iv = __expf(it - mn);
        float fv = __expf(ft + mc - mn);
        float zc = fminf(fmaxf(zt, -15.f), 15.f);
        float ez = __expf(2.f * zc);
        float tz = (ez - 1.f) * __builtin_amdgcn_rcpf(ez + 1.f);
        float cn = fv * cc + iv * tz;
        float nn = fv * nc + iv;
        float sg = __builtin_amdgcn_rcpf(1.f + __expf(-ot));
        float hn = sg * cn * __builtin_amdgcn_rcpf(nn);
        cc = cn; nc = nn; mc = mn;

        hsh[w][lane] = (f16)hn;      // next-step exchange (wave-local)
        hprev = hn; xprev = xc;
      }
    }
    // epilogue: groupnorm of step 127
    {
      uint hu[16];
      const uint* hp = (const uint*)&hsh[w][0];
      uint4 q0 = *(const uint4*)(hp + half * 16);
      uint4 q1 = *(const uint4*)(hp + half * 16 + 4);
      uint4 q2 = *(const uint4*)(hp + half * 16 + 8);
      uint4 q3 = *(const uint4*)(hp + half * 16 + 12);
      hu[0]=q0.x; hu[1]=q0.y; hu[2]=q0.z; hu[3]=q0.w;
      hu[4]=q1.x; hu[5]=q1.y; hu[6]=q1.z; hu[7]=q1.w;
      hu[8]=q2.x; hu[9]=q2.y; hu[10]=q2.z; hu[11]=q2.w;
      hu[12]=q3.x; hu[13]=q3.y; hu[14]=q3.z; hu[15]=q3.w;
      float s1 = 0.f, s2 = 0.f;
      #pragma unroll
      for (int j = 0; j < 16; ++j) {
        s1 = fdot2f(hu[j], one2, s1);
        s2 = fdot2f(hu[j], hu[j], s2);
      }
      float mu = s1 * (1.f / 32.f);
      float va = s2 * (1.f / 32.f) - mu * mu;
      float ov = xprev + (hprev - mu) * rsqrtf(va + 1e-5f) * gw;
      if (last) {
        psum += ov;
        pooled[b * Dn + d] = psum * (1.f / 128.f);
      } else {
        xo[(size_t)(Ln - 1) * Dn] = ov;
      }
    }
  };

  // ---------------- pipeline ----------------
  ln_phase(lnw, lnb, true);            // embed + LN0
  __syncthreads();
  gemm_phase(WhF, bg);
  __syncthreads();
  scan_phase(RT, gnw, 0);
  __syncthreads();
  ln_phase(lnw + Dn, lnb + Dn, false); // LN1 from updated x
  __syncthreads();
  gemm_phase(WhF + 65536, bg + Cn);
  __syncthreads();
  scan_phase(RT + 16384, gnw + Dn, 1);
}

// ---------------- head: MLP on pooled [512][128] ----------------
__global__ __launch_bounds__(64) void k_head(const float* __restrict__ pooled,
                                             const float* __restrict__ w1,
                                             const float* __restrict__ b1,
                                             const float* __restrict__ w2,
                                             const float* __restrict__ b2,
                                             float* __restrict__ out) {
  int b = blockIdx.x;
  int tid = threadIdx.x;  // 64
  __shared__ float pool[128];
  __shared__ float hid[64];
  pool[tid]      = pooled[b * Dn + tid];
  pool[tid + 64] = pooled[b * Dn + tid + 64];
  __syncthreads();
  {
    float a = b1[tid];
    const float* wr = w1 + (size_t)tid * Dn;
    #pragma unroll 4
    for (int dd = 0; dd < Dn; ++dd) a += pool[dd] * wr[dd];
    hid[tid] = fmaxf(a, 0.f);
  }
  __syncthreads();
  if (tid < 2) {
    float a = b2[tid];
    const float* wr = w2 + tid * 64;
    #pragma unroll 4
    for (int j = 0; j < 64; ++j) a += hid[j] * wr[j];
    out[b * 2 + tid] = a;
  }
}

extern "C" void kernel_launch(void* const* d_in, const int* in_sizes, int n_in,
                              void* d_out, int out_size, void* d_ws, size_t ws_size,
                              hipStream_t stream) {
  const int*   ids  = (const int*)d_in[0];
  const float* emb  = (const float*)d_in[1];
  const float* ln_w = (const float*)d_in[2];
  const float* ln_b = (const float*)d_in[3];
  const float* Wg   = (const float*)d_in[4];
  const float* Rg   = (const float*)d_in[5];
  const float* bg   = (const float*)d_in[6];
  const float* gn_w = (const float*)d_in[7];
  const float* w1   = (const float*)d_in[8];
  const float* b1   = (const float*)d_in[9];
  const float* w2   = (const float*)d_in[10];
  const float* b2   = (const float*)d_in[11];
  float* out = (float*)d_out;

  char* ws = (char*)d_ws;
  float* x     = (float*)ws;                                   // 512*136*128*4 = 35,651,584 B
  uint2* preP  = (uint2*)(ws + 35651584);                      // 512*136*128*8 = 71,303,168 B
  f16*   WhF   = (f16*)(ws + 35651584 + 71303168);             //    262,144 B
  f16*   RT    = (f16*)(ws + 106954752 + 262144);              //     65,536 B
  float* pooled= (float*)(ws + 107216896 + 65536);             //    262,144 B

  k_convert<<<192, 256, 0, stream>>>(Wg, Rg, WhF, RT);
  k_fused<<<512, 128, 0, stream>>>(ids, emb, ln_w, ln_b, WhF, RT, bg, gn_w,
                                   x, preP, pooled);
  k_head<<<512, 64, 0, stream>>>(pooled, w1, b1, w2, b2, out);
}